// Round 6
// baseline (98.282 us; speedup 1.0000x reference)
//
#include <hip/hip_runtime.h>

// MonotoneActivation: B=4096, G=512, K=4, D=8
// out[b, g*8+d] = sum_j coef_j * params[g, idx_j, d]
// Round 6 (= round-5 theory, compile-fixed): nontemporal builtins need a
// native clang vector type, not HIP_vector_type — use ext_vector f32x4.
// Round-3 mapping (1 thread per output float4 -> fully dense stores,
// 8.4 KB LDS -> high occupancy) + X register prefetch (ILP) + NONTEMPORAL
// load/store so the 64 MiB output stream doesn't write-allocate and evict
// L3-warm X. If neutral: mixed-stream HBM ceiling (32 MiB read + 64 MiB
// write mandatory) -> roofline.

typedef float f32x4 __attribute__((ext_vector_type(4)));

#define BB 4096
#define GG 512
#define G_TILE 16
#define NB 8            // b-iterations; 8 b-rows per iter -> 64 b per block
#define G_STRIDE 33     // float4 per g in LDS (32 + 1 pad)

__global__ __launch_bounds__(256) void monoact_kernel(
    const f32x4* __restrict__ X4,   // (B, 512) f32x4 view of X (B, 2048) fp32
    const f32x4* __restrict__ P4,   // (G, 32) f32x4 view of params (G,16,8) fp32
    f32x4* __restrict__ O4)         // (B, 1024) f32x4 view of out (B, 4096) fp32
{
    __shared__ f32x4 lds_p[G_TILE * G_STRIDE];   // 8448 B

    const int tid = threadIdx.x;
    const int g0 = blockIdx.x * G_TILE;
    const int b0 = blockIdx.y * (8 * NB);

    // Stage params[g0..g0+15] (512 f32x4) into LDS, padded layout.
    for (int j = tid; j < G_TILE * 32; j += 256) {
        const int g_l = j >> 5;
        const int rem = j & 31;
        lds_p[g_l * G_STRIDE + rem] = P4[(size_t)(g0 + g_l) * 32 + rem];
    }
    __syncthreads();

    const int gh  = tid & 31;        // g_l*2 + h
    const int g_l = gh >> 1;
    const int h   = gh & 1;          // which D-half (f32x4) of the output row
    const int b_l = tid >> 5;        // 0..7
    const int g = g0 + g_l;
    const f32x4* __restrict__ pg = lds_p + g_l * G_STRIDE + h;

    // Prefetch all NB X values (streaming loads; lane pairs share a line).
    f32x4 xs[NB];
#pragma unroll
    for (int it = 0; it < NB; ++it) {
        const int b = b0 + it * 8 + b_l;
        xs[it] = __builtin_nontemporal_load(&X4[(size_t)b * 512 + g]);
    }

#pragma unroll
    for (int it = 0; it < NB; ++it) {
        const int b = b0 + it * 8 + b_l;
        const f32x4 x = xs[it];

        float v[4] = {x.x, x.y, x.z, x.w};
        int   id[4] = {0, 1, 2, 3};
#define CSWAP(a, c)                                               \
        {                                                         \
            bool sw = v[a] > v[c];                                \
            float tv = sw ? v[a] : v[c];                          \
            v[a] = sw ? v[c] : v[a];                              \
            v[c] = tv;                                            \
            int ti = sw ? id[a] : id[c];                          \
            id[a] = sw ? id[c] : id[a];                           \
            id[c] = ti;                                           \
        }
        CSWAP(0, 1)
        CSWAP(2, 3)
        CSWAP(0, 2)
        CSWAP(1, 3)
        CSWAP(1, 2)
#undef CSWAP

        const float c0 = v[0];
        const float c1 = v[1] - v[0];
        const float c2 = v[2] - v[1];
        const float c3 = v[3] - v[2];

        const int r0 = 15;
        const int r1 = r0 - (1 << id[0]);
        const int r2 = r1 - (1 << id[1]);
        const int r3 = r2 - (1 << id[2]);

        const f32x4 a0 = pg[r0 * 2];
        const f32x4 a1 = pg[r1 * 2];
        const f32x4 a2 = pg[r2 * 2];
        const f32x4 a3 = pg[r3 * 2];

        f32x4 o;
        o.x = fmaf(c0, a0.x, fmaf(c1, a1.x, fmaf(c2, a2.x, c3 * a3.x)));
        o.y = fmaf(c0, a0.y, fmaf(c1, a1.y, fmaf(c2, a2.y, c3 * a3.y)));
        o.z = fmaf(c0, a0.z, fmaf(c1, a1.z, fmaf(c2, a2.z, c3 * a3.z)));
        o.w = fmaf(c0, a0.w, fmaf(c1, a1.w, fmaf(c2, a2.w, c3 * a3.w)));

        // 32 consecutive lanes -> 512 B dense; nontemporal: don't write-allocate.
        __builtin_nontemporal_store(o, &O4[(size_t)b * 1024 + (size_t)g0 * 2 + gh]);
    }
}

extern "C" void kernel_launch(void* const* d_in, const int* in_sizes, int n_in,
                              void* d_out, int out_size, void* d_ws, size_t ws_size,
                              hipStream_t stream) {
    const f32x4* X4 = (const f32x4*)d_in[0];   // X: (4096, 2048) fp32
    const f32x4* P4 = (const f32x4*)d_in[1];   // params: (512, 16, 8) fp32
    f32x4* O4 = (f32x4*)d_out;                 // out: (4096, 4096) fp32

    dim3 grid(GG / G_TILE, BB / (8 * NB));     // (32, 64) = 2048 blocks
    monoact_kernel<<<grid, 256, 0, stream>>>(X4, P4, O4);
}

// Round 7
// 95.786 us; speedup vs baseline: 1.0261x; 1.0261x over previous
//
#include <hip/hip_runtime.h>

// MonotoneActivation: B=4096, G=512, K=4, D=8
// out[b, g*8+d] = sum_j coef_j * params[g, idx_j, d]
// Round 7 = revert to round-3 (best measured, 94.9 µs): one thread per
// OUTPUT float4 (2 threads per (b,g), h = D-half), fully dense stores
// (32 lanes -> 512 contiguous bytes), 8.4 KB LDS params stage, plain
// cached loads/stores (nontemporal hurt: bypassing L2 write-combining
// cost more than the pollution it avoided).
//
// Ceiling analysis: kernel traffic is mandatory (32 MiB X read + 64 MiB
// fp32 out write); the timed window also contains ~400 MB of harness
// poison-fill/restore traffic. Three structural kernel variants (r3/r4/r6)
// all landed within ±2 µs => the window is aggregate-HBM-bound.

#define BB 4096
#define GG 512
#define G_TILE 16
#define NB 8            // b-iterations; 8 b-rows per iter -> 64 b per block
#define G_STRIDE 33     // float4 per g in LDS (32 + 1 pad)

__global__ __launch_bounds__(256) void monoact_kernel(
    const float4* __restrict__ X4,   // (B, 512) float4 view of X (B, 2048) fp32
    const float4* __restrict__ P4,   // (G, 32) float4 view of params (G,16,8) fp32
    float4* __restrict__ O4)         // (B, 1024) float4 view of out (B, 4096) fp32
{
    __shared__ float4 lds_p[G_TILE * G_STRIDE];   // 8448 B

    const int tid = threadIdx.x;
    const int g0 = blockIdx.x * G_TILE;
    const int b0 = blockIdx.y * (8 * NB);

    // Stage params[g0..g0+15] (512 float4) into LDS, padded layout.
    for (int j = tid; j < G_TILE * 32; j += 256) {
        const int g_l = j >> 5;
        const int rem = j & 31;
        lds_p[g_l * G_STRIDE + rem] = P4[(size_t)(g0 + g_l) * 32 + rem];
    }
    __syncthreads();

    const int gh  = tid & 31;        // g_l*2 + h
    const int g_l = gh >> 1;
    const int h   = gh & 1;          // which D-half (float4) of the output row
    const int b_l = tid >> 5;        // 0..7
    const int g = g0 + g_l;
    const float4* __restrict__ pg = lds_p + g_l * G_STRIDE + h;

    for (int it = 0; it < NB; ++it) {
        const int b = b0 + it * 8 + b_l;

        const float4 x = X4[(size_t)b * 512 + g];   // lane pair shares this line

        float v[4] = {x.x, x.y, x.z, x.w};
        int   id[4] = {0, 1, 2, 3};
#define CSWAP(a, c)                                               \
        {                                                         \
            bool sw = v[a] > v[c];                                \
            float tv = sw ? v[a] : v[c];                          \
            v[a] = sw ? v[c] : v[a];                              \
            v[c] = tv;                                            \
            int ti = sw ? id[a] : id[c];                          \
            id[a] = sw ? id[c] : id[a];                           \
            id[c] = ti;                                           \
        }
        CSWAP(0, 1)
        CSWAP(2, 3)
        CSWAP(0, 2)
        CSWAP(1, 3)
        CSWAP(1, 2)
#undef CSWAP

        const float c0 = v[0];
        const float c1 = v[1] - v[0];
        const float c2 = v[2] - v[1];
        const float c3 = v[3] - v[2];

        const int r0 = 15;
        const int r1 = r0 - (1 << id[0]);
        const int r2 = r1 - (1 << id[1]);
        const int r3 = r2 - (1 << id[2]);

        const float4 a0 = pg[r0 * 2];
        const float4 a1 = pg[r1 * 2];
        const float4 a2 = pg[r2 * 2];
        const float4 a3 = pg[r3 * 2];

        float4 o;
        o.x = fmaf(c0, a0.x, fmaf(c1, a1.x, fmaf(c2, a2.x, c3 * a3.x)));
        o.y = fmaf(c0, a0.y, fmaf(c1, a1.y, fmaf(c2, a2.y, c3 * a3.y)));
        o.z = fmaf(c0, a0.z, fmaf(c1, a1.z, fmaf(c2, a2.z, c3 * a3.z)));
        o.w = fmaf(c0, a0.w, fmaf(c1, a1.w, fmaf(c2, a2.w, c3 * a3.w)));

        // 32 consecutive lanes -> 512 B fully-dense contiguous store per b-row.
        O4[(size_t)b * 1024 + (size_t)g0 * 2 + gh] = o;
    }
}

extern "C" void kernel_launch(void* const* d_in, const int* in_sizes, int n_in,
                              void* d_out, int out_size, void* d_ws, size_t ws_size,
                              hipStream_t stream) {
    const float4* X4 = (const float4*)d_in[0];   // X: (4096, 2048) fp32
    const float4* P4 = (const float4*)d_in[1];   // params: (512, 16, 8) fp32
    float4* O4 = (float4*)d_out;                 // out: (4096, 4096) fp32

    dim3 grid(GG / G_TILE, BB / (8 * NB));       // (32, 64) = 2048 blocks
    monoact_kernel<<<grid, 256, 0, stream>>>(X4, P4, O4);
}